// Round 1
// baseline (1451.573 us; speedup 1.0000x reference)
//
#include <hip/hip_runtime.h>
#include <math.h>

#define BATCH 1024
#define TSEQ  2048
#define DIN   5
#define H     64
#define BT    4      // elems per block; grid 256 = every CU
#define SSTR  144    // halves/elem: [h1 64 | h2 64 | pad 16] -> exact 2-way banks (free)
#define NOUT  128

typedef _Float16 f16x8 __attribute__((ext_vector_type(8)));
typedef float    f32x4 __attribute__((ext_vector_type(4)));

#if __has_builtin(__builtin_amdgcn_rcpf)
__device__ __forceinline__ float rcp_fast(float x) { return __builtin_amdgcn_rcpf(x); }
#else
__device__ __forceinline__ float rcp_fast(float x) { return 1.0f / x; }
#endif

#define LOG2E 1.44269504088896f
#define MFMA16(A, B, C) __builtin_amdgcn_mfma_f32_16x16x32_f16((A), (B), (C), 0, 0, 0)

// exp2-based activations; weights/biases pre-scaled by log2e (sigmoid) or
// 2*log2e (tanh gate) so no per-use multiply.
__device__ __forceinline__ float sigm2(float s) {   // s = log2e * p
    return rcp_fast(1.0f + __builtin_amdgcn_exp2f(-s));
}
__device__ __forceinline__ float tanh2(float s) {   // s = 2*log2e * p
    return fmaf(-2.0f, rcp_fast(__builtin_amdgcn_exp2f(s) + 1.0f), 1.0f);
}

// MERGED-LAYER waves: 4 waves/block (256 thr), each wave owns ONE 16-unit
// tile (ww) and computes BOTH layer-1(t=i) and layer-2(t=i-1) for it.
//  - a0/a1 (= h1(i-1) = y1 input of layer-2) are read ONCE and feed both
//    layers' MFMAs: LDS reads 24 -> 16 b128 per CU-iter.
//  - one long instruction stream per wave: lay-1 gates interleave under
//    lay-2 MFMAs; dx (x-projection for t=i) MFMAs sit at the loop head to
//    cover post-barrier ds_read latency.
//  - lay-2 accumulation split into two 2-deep chains (y1-part from bias,
//    h2-part from zero) combined by a scalar add of element 0 only.
// Same data flow / LDS layout / skew as the 8-wave version; barrier now
// syncs 4 waves (one per SIMD).
__global__ __launch_bounds__(256, 1)
void lstm_mfma(const float* __restrict__ x,
               const float* __restrict__ Wih0, const float* __restrict__ Whh0,
               const float* __restrict__ bih0, const float* __restrict__ bhh0,
               const float* __restrict__ Wih1, const float* __restrict__ Whh1,
               const float* __restrict__ bih1, const float* __restrict__ bhh1,
               const float* __restrict__ Wfc,  const float* __restrict__ bfc,
               float* __restrict__ out)
{
    __shared__ alignas(16) _Float16 S[2][BT * SSTR];   // 2.25 KB state, double-buffered
    __shared__ alignas(16) float    h2f[BT][H];        // 1 KB final h2 for FC

    const int tid  = threadIdx.x;
    const int ww   = tid >> 6;         // 0..3 unit tile
    const int lane = tid & 63;
    const int col  = lane & 15;        // n (h-unit offset); A-row m
    const int q    = lane >> 4;        // quad -> batch elem; k-slice
    const int hu   = 16 * ww + col;
    const int b0   = blockIdx.x * BT;

    // ---- zero both state buffers ----
    for (int j = tid; j < 2 * BT * SSTR; j += 256)
        ((_Float16*)S)[j] = (_Float16)0.0f;

    const float sgl[4] = {LOG2E, LOG2E, 2.0f * LOG2E, LOG2E};  // i,f,g,o

    // ---- B-fragments for BOTH layers (registers, pre-scaled) ----
    // B[k=q*8+j][n=col]; n-tile: gate rows g*64 + hu.
    f16x8 Bh[4][2];   // lay1: Whh0 k0-31 / k32-63
    f16x8 Bx[4];      // lay1: Wih0 (5 of 32; zero for q!=0)
    f16x8 C2[4][4];   // lay2: [Wih1 k0 | Wih1 k1 | Whh1 k0 | Whh1 k1]
    f32x4 bC1[4], bC2[4];
    #pragma unroll
    for (int g = 0; g < 4; ++g) {
        const int   row = g * 64 + hu;
        const float sg  = sgl[g];
        const float* wh0 = Whh0 + row * H;
        const float* wi1 = Wih1 + row * H;
        const float* wh1 = Whh1 + row * H;
        #pragma unroll
        for (int j = 0; j < 8; ++j) {
            const int k = q * 8 + j;
            Bh[g][0][j] = (_Float16)(wh0[k]      * sg);
            Bh[g][1][j] = (_Float16)(wh0[32 + k] * sg);
            C2[g][0][j] = (_Float16)(wi1[k]      * sg);
            C2[g][1][j] = (_Float16)(wi1[32 + k] * sg);
            C2[g][2][j] = (_Float16)(wh1[k]      * sg);
            C2[g][3][j] = (_Float16)(wh1[32 + k] * sg);
            Bx[g][j]    = (_Float16)(k < DIN ? Wih0[row * DIN + k] * sg : 0.0f);
        }
        const float b1 = (bih0[row] + bhh0[row]) * sg;
        const float b2 = (bih1[row] + bhh1[row]) * sg;
        bC1[g] = f32x4{b1, b1, b1, b1};
        bC2[g] = f32x4{b2, b2, b2, b2};
    }

    // ---- x pipeline: raw floats carried in regs, cvt+dx at loop HEAD ----
    // Only q==0 lanes carry real x (B's k>=8 rows are zero), elem = col>>2.
    const float* xp = x + (size_t)(b0 + (col >> 2)) * TSEQ * DIN;
    float x0 = 0.f, x1 = 0.f, x2 = 0.f, x3 = 0.f, x4 = 0.f;
    if (q == 0) { x0 = xp[0]; x1 = xp[1]; x2 = xp[2]; x3 = xp[3]; x4 = xp[4]; }
    xp += DIN;      // -> t=1

    f16x8 ax = {(_Float16)0.0f, (_Float16)0.0f, (_Float16)0.0f, (_Float16)0.0f,
                (_Float16)0.0f, (_Float16)0.0f, (_Float16)0.0f, (_Float16)0.0f};

    const int ab  = (col >> 2) * SSTR + q * 8;   // A-frag read base (halves)
    const int wb1 = q * SSTR + hu;               // h1 write slot
    const int wb2 = q * SSTR + 64 + hu;          // h2 write slot
    float cst1 = 0.f, cst2 = 0.f, h2fin = 0.f;

    __syncthreads();

    // ============ main loop: iter i = layer-1(t=i) & layer-2(t=i-1) ============
    #pragma unroll 1
    for (int i = 0; i <= TSEQ; ++i) {
        const _Float16* rb   = S[(i + 1) & 1];
        _Float16*       wbuf = S[i & 1];

        // issue all state reads first (a0/a1 shared by both layers)
        f16x8 a0  = *(const f16x8*)&rb[ab];        // h1(i-1) k 0..31  (= y1 for lay-2)
        f16x8 a1  = *(const f16x8*)&rb[ab + 32];   // h1(i-1) k 32..63
        f16x8 ah0 = *(const f16x8*)&rb[ab + 64];   // h2(i-2) k 0..31
        f16x8 ah1 = *(const f16x8*)&rb[ab + 96];   // h2(i-2) k 32..63

        // dx for lay-1 t=i (x loaded last iter) — independent MFMAs that
        // cover the ds_read latency right after the barrier.
        if (q == 0) {
            ax[0] = (_Float16)x0; ax[1] = (_Float16)x1; ax[2] = (_Float16)x2;
            ax[3] = (_Float16)x3; ax[4] = (_Float16)x4;
        }
        f32x4 dx[4];
        #pragma unroll
        for (int g = 0; g < 4; ++g)
            dx[g] = MFMA16(ax, Bx[g], bC1[g]);

        // fire next-x loads (consumed next iteration; ample slack)
        if (q == 0 && i + 1 < TSEQ) { x0 = xp[0]; x1 = xp[1]; x2 = xp[2]; x3 = xp[3]; x4 = xp[4]; }
        xp += DIN;

        // 24 MFMAs in 12 independent 2-deep chains
        f32x4 d[4], e2[4], f2[4];
        const f32x4 z4 = {0.f, 0.f, 0.f, 0.f};
        #pragma unroll
        for (int g = 0; g < 4; ++g) {
            d[g]  = MFMA16(a0,  Bh[g][0], dx[g]);      // lay-1: h1 part on top of x+bias
            d[g]  = MFMA16(a1,  Bh[g][1], d[g]);
            e2[g] = MFMA16(a0,  C2[g][0], bC2[g]);     // lay-2: y1 part + bias
            e2[g] = MFMA16(a1,  C2[g][1], e2[g]);
            f2[g] = MFMA16(ah0, C2[g][2], z4);         // lay-2: h2 part
            f2[g] = MFMA16(ah1, C2[g][3], f2[g]);
        }

        if (i < TSEQ) {   // layer-1 gates for t=i
            float iv = sigm2(d[0][0]);
            float fv = sigm2(d[1][0]);
            float gv = tanh2(d[2][0]);
            float ov = sigm2(d[3][0]);
            cst1 = fmaf(fv, cst1, iv * gv);
            wbuf[wb1] = (_Float16)(ov * tanh2(2.0f * LOG2E * cst1));
        }
        if (i > 0) {      // layer-2 gates for t=i-1 (combine split chains: elem 0 only)
            float p0 = e2[0][0] + f2[0][0];
            float p1 = e2[1][0] + f2[1][0];
            float p2 = e2[2][0] + f2[2][0];
            float p3 = e2[3][0] + f2[3][0];
            float iv = sigm2(p0);
            float fv = sigm2(p1);
            float gv = tanh2(p2);
            float ov = sigm2(p3);
            cst2 = fmaf(fv, cst2, iv * gv);
            h2fin = ov * tanh2(2.0f * LOG2E * cst2);
            wbuf[wb2] = (_Float16)h2fin;
        }
        __syncthreads();
    }

    // ---------------- epilogue: out = relu(h2(T-1) @ Wfc^T + bfc) ----------------
    h2f[q][hu] = h2fin;     // all 256 threads: (elem q, unit hu) unique
    __syncthreads();
    {
        const int o  = tid & (NOUT - 1);   // 0..127
        const int eh = tid >> 7;           // 0..1 -> elems {eh, eh+2}
        const float4* wr = (const float4*)(Wfc + o * H);
        #pragma unroll
        for (int e = eh; e < BT; e += 2) {
            const float* hv = h2f[e];
            float s0 = 0.f, s1 = 0.f, s2 = 0.f, s3 = 0.f;
            #pragma unroll
            for (int k = 0; k < H / 4; ++k) {
                float4 wv = wr[k];
                s0 = fmaf(wv.x, hv[4 * k + 0], s0);
                s1 = fmaf(wv.y, hv[4 * k + 1], s1);
                s2 = fmaf(wv.z, hv[4 * k + 2], s2);
                s3 = fmaf(wv.w, hv[4 * k + 3], s3);
            }
            float acc = bfc[o] + (s0 + s1) + (s2 + s3);
            out[(size_t)(b0 + e) * NOUT + o] = fmaxf(acc, 0.0f);
        }
    }
}

extern "C" void kernel_launch(void* const* d_in, const int* in_sizes, int n_in,
                              void* d_out, int out_size, void* d_ws, size_t ws_size,
                              hipStream_t stream) {
    const float* x    = (const float*)d_in[0];
    const float* Wih0 = (const float*)d_in[1];
    const float* Whh0 = (const float*)d_in[2];
    const float* bih0 = (const float*)d_in[3];
    const float* bhh0 = (const float*)d_in[4];
    const float* Wih1 = (const float*)d_in[5];
    const float* Whh1 = (const float*)d_in[6];
    const float* bih1 = (const float*)d_in[7];
    const float* bhh1 = (const float*)d_in[8];
    const float* Wfc  = (const float*)d_in[9];
    const float* bfc  = (const float*)d_in[10];
    float* out = (float*)d_out;

    lstm_mfma<<<dim3(BATCH / BT), dim3(256), 0, stream>>>(
        x, Wih0, Whh0, bih0, bhh0, Wih1, Whh1, bih1, bhh1, Wfc, bfc, out);
}

// Round 2
// 1003.462 us; speedup vs baseline: 1.4466x; 1.4466x over previous
//
#include <hip/hip_runtime.h>
#include <math.h>

#define BATCH 1024
#define TSEQ  2048
#define DIN   5
#define H     64
#define BT    4      // elems per block; grid 256 = every CU
#define SSTR  144    // halves/elem: [h1 64 | h2 64 | pad 16] -> exact 2-way banks (free)
#define NOUT  128

typedef _Float16 f16x8 __attribute__((ext_vector_type(8)));
typedef float    f32x4 __attribute__((ext_vector_type(4)));

#if __has_builtin(__builtin_amdgcn_rcpf)
__device__ __forceinline__ float rcp_fast(float x) { return __builtin_amdgcn_rcpf(x); }
#else
__device__ __forceinline__ float rcp_fast(float x) { return 1.0f / x; }
#endif

#define LOG2E 1.44269504088896f
#define MFMA16(A, B, C) __builtin_amdgcn_mfma_f32_16x16x32_f16((A), (B), (C), 0, 0, 0)

// exp2-based activations; weights/biases pre-scaled by log2e (sigmoid) or
// 2*log2e (tanh gate) so no per-use multiply.
__device__ __forceinline__ float sigm2(float s) {   // s = log2e * p
    return rcp_fast(1.0f + __builtin_amdgcn_exp2f(-s));
}
__device__ __forceinline__ float tanh2(float s) {   // s = 2*log2e * p
    return fmaf(-2.0f, rcp_fast(__builtin_amdgcn_exp2f(s) + 1.0f), 1.0f);
}

// lgkm-only barrier: ds_write visibility without draining vmcnt, so the
// x prefetch loads stay in flight ACROSS the barrier (counted vmcnt at use).
__device__ __forceinline__ void sync_lgkm() {
    asm volatile("s_waitcnt lgkmcnt(0)" ::: "memory");
    __builtin_amdgcn_s_barrier();
    asm volatile("" ::: "memory");
}

// r8 skeleton (512 thr = 8 waves, layer-split: SIMD s hosts wave s (lay-1)
// + wave s+4 (lay-2); 2 waves/SIMD for MFMA||VALU cross-wave overlap) with:
//  - lgkm-only barrier: x global loads cross the barrier (old __syncthreads
//    forced vmcnt(0) -> full HBM/L3 round trip inside every iteration wall).
//  - x-projection on the VALU (20 f32 fma -> C elem 0), not MFMA: cuts
//    per-SIMD matrix issue 28 -> 24 and drops the f16 cvt chain.
//  - s_setprio(1) around MFMA clusters (lay-1/lay-2 role diversity).
__global__ __launch_bounds__(512)
void lstm_mfma(const float* __restrict__ x,
               const float* __restrict__ Wih0, const float* __restrict__ Whh0,
               const float* __restrict__ bih0, const float* __restrict__ bhh0,
               const float* __restrict__ Wih1, const float* __restrict__ Whh1,
               const float* __restrict__ bih1, const float* __restrict__ bhh1,
               const float* __restrict__ Wfc,  const float* __restrict__ bfc,
               float* __restrict__ out)
{
    __shared__ alignas(16) _Float16 S[2][BT * SSTR];   // 2.25 KB state, double-buffered
    __shared__ alignas(16) float    h2f[BT][H];        // 1 KB final h2 for FC

    const int tid  = threadIdx.x;
    const int w    = tid >> 6;         // 0..7
    const int lane = tid & 63;
    const int col  = lane & 15;        // n (h-unit offset); A-row m
    const int q    = lane >> 4;        // quad -> C/D row group; k-slice
    const int ww   = w & 3;            // h-unit tile
    const int lay  = w >> 2;           // 0 = layer-1, 1 = layer-2
    const int hu   = 16 * ww + col;
    const int b0   = blockIdx.x * BT;

    // ---- zero both state buffers ----
    for (int j = tid; j < 2 * BT * SSTR; j += 512)
        ((_Float16*)S)[j] = (_Float16)0.0f;

    const float sgl[4] = {LOG2E, LOG2E, 2.0f * LOG2E, LOG2E};  // i,f,g,o

    // ---- B-fragments for THIS wave's layer (registers, pre-scaled) ----
    // B[k=q*8+j][n=col]; n-tile: gate rows g*64 + hu.
    // lay0: [0]=Whh0 k0-31 [1]=Whh0 k32-63  (+ wx/b1s for the VALU x-proj)
    // lay1: [0]=Wih1 k0-31 [1]=Wih1 k32-63 [2]=Whh1 k0-31 [3]=Whh1 k32-63
    f16x8 Bf[4][4];
    f32x4 bC[4];        // lay-2 bias as MFMA C
    float wx[4][DIN];   // lay-1: Wih0 row (pre-scaled), f32
    float b1s[4];       // lay-1 scalar bias
    #pragma unroll
    for (int g = 0; g < 4; ++g) {
        const int   row = g * 64 + hu;
        const float sg  = sgl[g];
        if (lay) {
            const float* wa = Wih1 + row * H;
            const float* wb = Whh1 + row * H;
            #pragma unroll
            for (int j = 0; j < 8; ++j) {
                const int k = q * 8 + j;
                Bf[g][0][j] = (_Float16)(wa[k]      * sg);
                Bf[g][1][j] = (_Float16)(wa[32 + k] * sg);
                Bf[g][2][j] = (_Float16)(wb[k]      * sg);
                Bf[g][3][j] = (_Float16)(wb[32 + k] * sg);
            }
            const float bb = (bih1[row] + bhh1[row]) * sg;
            bC[g] = f32x4{bb, bb, bb, bb};
        } else {
            const float* wh = Whh0 + row * H;
            #pragma unroll
            for (int j = 0; j < 8; ++j) {
                const int k = q * 8 + j;
                Bf[g][0][j] = (_Float16)(wh[k]      * sg);
                Bf[g][1][j] = (_Float16)(wh[32 + k] * sg);
            }
            #pragma unroll
            for (int j = 0; j < DIN; ++j)
                wx[g][j] = Wih0[row * DIN + j] * sg;
            b1s[g] = (bih0[row] + bhh0[row]) * sg;
        }
    }

    // ---- x pipeline: every lay-0 lane carries x of elem q (f32, registers) ----
    // (dxs feeds MFMA C element 0 = D row 4q = elem q, so x index is q.)
    const float* xq = x + (size_t)(b0 + q) * TSEQ * DIN;
    float x0 = 0.f, x1 = 0.f, x2 = 0.f, x3 = 0.f, x4 = 0.f;
    if (lay == 0) {
        x0 = xq[0]; x1 = xq[1]; x2 = xq[2]; x3 = xq[3]; x4 = xq[4];
        xq += DIN;      // -> t=1
    }

    const int ab  = (col >> 2) * SSTR + q * 8;   // A-frag read base (halves)
    const int wb1 = q * SSTR + hu;               // h1 write slot
    const int wb2 = q * SSTR + 64 + hu;          // h2 write slot
    float cst = 0.0f, h2fin = 0.0f;

    __syncthreads();

    // ============ main loop: iter i = layer-1(t=i) & layer-2(t=i-1) ============
    #pragma unroll 1
    for (int i = 0; i <= TSEQ; ++i) {
        const _Float16* rb   = S[(i + 1) & 1];
        _Float16*       wbuf = S[i & 1];

        if (lay == 0) {
            // fire next-x loads FIRST: they stay in flight across sync_lgkm,
            // consumed next iteration (~1 full wall of latency budget).
            const bool ld = (i + 1 < TSEQ);
            float n0, n1, n2, n3, n4;
            if (ld) { n0 = xq[0]; n1 = xq[1]; n2 = xq[2]; n3 = xq[3]; n4 = xq[4]; xq += DIN; }

            f16x8 a0 = *(const f16x8*)&rb[ab];        // h1 k 0..31
            f16x8 a1 = *(const f16x8*)&rb[ab + 32];   // h1 k 32..63

            // x-projection on the VALU (f32), overlaps ds_read latency
            float dxs[4];
            #pragma unroll
            for (int g = 0; g < 4; ++g) {
                float s = fmaf(x0, wx[g][0], b1s[g]);
                s = fmaf(x1, wx[g][1], s);
                s = fmaf(x2, wx[g][2], s);
                s = fmaf(x3, wx[g][3], s);
                dxs[g] = fmaf(x4, wx[g][4], s);
            }

            f32x4 d[4];
            __builtin_amdgcn_s_setprio(1);
            #pragma unroll
            for (int g = 0; g < 4; ++g) {             // 2-deep chains, 4-way ILP
                f32x4 c0 = {dxs[g], 0.f, 0.f, 0.f};   // only D row 4q (elem q) is read
                d[g] = MFMA16(a0, Bf[g][0], c0);
                d[g] = MFMA16(a1, Bf[g][1], d[g]);
            }
            __builtin_amdgcn_s_setprio(0);

            if (i < TSEQ) {   // layer-1 G for t=i
                float iv = sigm2(d[0][0]);
                float fv = sigm2(d[1][0]);
                float gv = tanh2(d[2][0]);
                float ov = sigm2(d[3][0]);
                cst = fmaf(fv, cst, iv * gv);
                wbuf[wb1] = (_Float16)(ov * tanh2(2.0f * LOG2E * cst));
            }
            if (ld) { x0 = n0; x1 = n1; x2 = n2; x3 = n3; x4 = n4; }
        } else {
            f16x8 ay0 = *(const f16x8*)&rb[ab];        // y1(t-1) k 0..31
            f16x8 ay1 = *(const f16x8*)&rb[ab + 32];   // y1(t-1) k 32..63
            f16x8 ah0 = *(const f16x8*)&rb[ab + 64];   // h2(t-2) k 0..31
            f16x8 ah1 = *(const f16x8*)&rb[ab + 96];   // h2(t-2) k 32..63
            f32x4 d[4];
            __builtin_amdgcn_s_setprio(1);
            #pragma unroll
            for (int g = 0; g < 4; ++g) {
                d[g] = MFMA16(ay0, Bf[g][0], bC[g]);
                d[g] = MFMA16(ay1, Bf[g][1], d[g]);
                d[g] = MFMA16(ah0, Bf[g][2], d[g]);
                d[g] = MFMA16(ah1, Bf[g][3], d[g]);
            }
            __builtin_amdgcn_s_setprio(0);
            if (i > 0) {      // layer-2 G for t=i-1
                float iv = sigm2(d[0][0]);
                float fv = sigm2(d[1][0]);
                float gv = tanh2(d[2][0]);
                float ov = sigm2(d[3][0]);
                cst = fmaf(fv, cst, iv * gv);
                h2fin = ov * tanh2(2.0f * LOG2E * cst);
                wbuf[wb2] = (_Float16)h2fin;
            }
        }
        sync_lgkm();
    }

    // ---------------- epilogue: out = relu(h2(T-1) @ Wfc^T + bfc) ----------------
    if (lay) h2f[q][hu] = h2fin;
    __syncthreads();
    {
        const int e = tid >> 7;            // 0..3
        const int o = tid & (NOUT - 1);    // 0..127
        const float4* wr = (const float4*)(Wfc + o * H);
        const float*  hv = h2f[e];
        float s0 = 0.f, s1 = 0.f, s2 = 0.f, s3 = 0.f;
        #pragma unroll
        for (int k = 0; k < H / 4; ++k) {
            float4 wv = wr[k];
            s0 = fmaf(wv.x, hv[4 * k + 0], s0);
            s1 = fmaf(wv.y, hv[4 * k + 1], s1);
            s2 = fmaf(wv.z, hv[4 * k + 2], s2);
            s3 = fmaf(wv.w, hv[4 * k + 3], s3);
        }
        float acc = bfc[o] + (s0 + s1) + (s2 + s3);
        out[(size_t)(b0 + e) * NOUT + o] = fmaxf(acc, 0.0f);
    }
}

extern "C" void kernel_launch(void* const* d_in, const int* in_sizes, int n_in,
                              void* d_out, int out_size, void* d_ws, size_t ws_size,
                              hipStream_t stream) {
    const float* x    = (const float*)d_in[0];
    const float* Wih0 = (const float*)d_in[1];
    const float* Whh0 = (const float*)d_in[2];
    const float* bih0 = (const float*)d_in[3];
    const float* bhh0 = (const float*)d_in[4];
    const float* Wih1 = (const float*)d_in[5];
    const float* Whh1 = (const float*)d_in[6];
    const float* bih1 = (const float*)d_in[7];
    const float* bhh1 = (const float*)d_in[8];
    const float* Wfc  = (const float*)d_in[9];
    const float* bfc  = (const float*)d_in[10];
    float* out = (float*)d_out;

    lstm_mfma<<<dim3(BATCH / BT), dim3(512), 0, stream>>>(
        x, Wih0, Whh0, bih0, bhh0, Wih1, Whh1, bih1, bhh1, Wfc, bfc, out);
}